// Round 9
// baseline (484.318 us; speedup 1.0000x reference)
//
#include <hip/hip_runtime.h>
#include <math.h>

// GCN: h = elu(D^-1/2 (A+I) D^-1/2 (h W) + b [+ resid])
// N=100000 nodes, E=1600000 edges, 128 features per layer.
//
// R16 changes vs R15 (450us, agg 64.4us @ VALU 33%, 4.0 TB/s):
//  R15 evidence: 9us VALU cut bought 0.8us -> memory-side bound, but
//  Little's law says ~96 outstanding reqs/CU vs ~290 needed for peak:
//  still concurrency-limited, not BW-limited.
//  - Aggregate redesigned: one 16-lane QUARTER per node (4 nodes/wave).
//    Lane l owns features 8l..8l+7 = its 16B gather fragment. One gather
//    instruction now carries 4 independent rows (4x address streams).
//  - ZERO __shfl (was 8/16 edges), ZERO cross-lane reduce (was 16 packed
//    ops): per-lane accumulator is already the final per-feature sum.
//  - colw -> colw2 u64 {bo = src*256, wpk = f16(w) duplicated}: zero
//    per-edge VALU prep (bo/wpk are direct register halves of the load).
//  - Tail: branch-free index-clamp (stays in [beg,end)) + weight zeroing.
//  - Divergence: wave runs max(deg of its 4 nodes) ~21 vs mean 17; paid
//    for by removed shfl/reduce.

#define NFEAT 128
#define LDSP 136   // LDS row pitch in shorts (128 + 8 pad)
#define BSH 9      // bucket shift: 512 nodes/bucket
#define BWID 512

typedef short short8 __attribute__((ext_vector_type(8)));
typedef unsigned short ushort8 __attribute__((ext_vector_type(8)));
typedef _Float16 half8 __attribute__((ext_vector_type(8)));
typedef _Float16 h16x2 __attribute__((ext_vector_type(2)));
typedef float f32x4 __attribute__((ext_vector_type(4)));
typedef float f32x2 __attribute__((ext_vector_type(2)));
typedef int i32x4 __attribute__((ext_vector_type(4)));

static __device__ __forceinline__ unsigned short f2bf(float f) {
  union { float f; unsigned int u; } v; v.f = f;
  unsigned int r = v.u + 0x7fffu + ((v.u >> 16) & 1u);  // RNE (finite values)
  return (unsigned short)(r >> 16);
}
static __device__ __forceinline__ unsigned short f2h(float f) {
  union { _Float16 h; unsigned short u; } c; c.h = (_Float16)f; return c.u;
}
static __device__ __forceinline__ h16x2 u2h2(unsigned int u) {
  union { unsigned int i; h16x2 h; } c; c.i = u; return c.h;
}
static __device__ __forceinline__ float elu_fast(float a) {
  return a > 0.0f ? a : (__expf(a) - 1.0f);
}

// ---------------- GEMM body, fp32 input -> bf16 MFMA, f16 out (L0) ----
static __device__ __forceinline__ void gemm_body(
    int gblk, const float* __restrict__ h, const unsigned short* __restrict__ Wt,
    unsigned short* __restrict__ out, int n, unsigned short* lds) {
  int t = threadIdx.x;
  int block0 = gblk * 64;

  const f32x4* h4 = (const f32x4*)h;
  #pragma unroll
  for (int i = 0; i < 8; ++i) {
    int idx = t + 256 * i;          // 0..2047
    int r = idx >> 5, c = idx & 31; // row, float4-col
    int grow = block0 + r; if (grow >= n) grow = n - 1;
    f32x4 v = __builtin_nontemporal_load(&h4[(size_t)grow * 32 + c]);
    ushort4 b;
    b.x = f2bf(v.x); b.y = f2bf(v.y); b.z = f2bf(v.z); b.w = f2bf(v.w);
    *(ushort4*)&lds[r * LDSP + c * 4] = b;
  }
  __syncthreads();

  int lane = t & 63, wave = t >> 6;
  int row16 = lane & 15;
  int kgrp = lane >> 4;

  short8 afrag[4];
  #pragma unroll
  for (int ks = 0; ks < 4; ++ks)
    afrag[ks] =
        *(const short8*)&lds[(wave * 16 + row16) * LDSP + ks * 32 + kgrp * 8];

  f32x4 acc[8];
  #pragma unroll
  for (int ct = 0; ct < 8; ++ct) {
    acc[ct] = (f32x4){0.0f, 0.0f, 0.0f, 0.0f};
    const short8* wrow =
        (const short8*)(Wt + (size_t)(ct * 16 + row16) * NFEAT);
    #pragma unroll
    for (int ks = 0; ks < 4; ++ks) {
      acc[ct] = __builtin_amdgcn_mfma_f32_16x16x32_bf16(
          wrow[ks * 4 + kgrp], afrag[ks], acc[ct], 0, 0, 0);
    }
  }

  int orow = block0 + wave * 16 + row16;
  if (orow < n) {
    unsigned short* op = out + (size_t)orow * NFEAT + kgrp * 4;
    #pragma unroll
    for (int ct = 0; ct < 8; ++ct) {
      ushort4 o;
      o.x = f2h(acc[ct][0]); o.y = f2h(acc[ct][1]);
      o.z = f2h(acc[ct][2]); o.w = f2h(acc[ct][3]);
      *(ushort4*)(op + ct * 16) = o;
    }
  }
}

// ---------------- GEMM, f16 input -> f16 MFMA, f16 out (L1, L2) -------
__global__ __launch_bounds__(256) void gemm_f16_kernel(
    const unsigned short* __restrict__ h16,  // f16 bits [n][128]
    const unsigned short* __restrict__ Wt,   // f16 bits [128][128] (n-major)
    unsigned short* __restrict__ out, int n) {
  __shared__ int lds_i[64 * LDSP / 2];
  unsigned short* lds = (unsigned short*)lds_i;
  int t = threadIdx.x;
  int block0 = blockIdx.x * 64;

  const ushort8* h8 = (const ushort8*)h16;
  #pragma unroll
  for (int i = 0; i < 4; ++i) {
    int idx = t + 256 * i;          // 0..1023
    int r = idx >> 4, c = idx & 15; // row, 8-elem col
    int grow = block0 + r; if (grow >= n) grow = n - 1;
    ushort8 v = __builtin_nontemporal_load(&h8[(size_t)grow * 16 + c]);
    *(ushort8*)&lds[r * LDSP + c * 8] = v;
  }
  __syncthreads();

  int lane = t & 63, wave = t >> 6;
  int row16 = lane & 15;
  int kgrp = lane >> 4;

  half8 afrag[4];
  #pragma unroll
  for (int ks = 0; ks < 4; ++ks)
    afrag[ks] =
        *(const half8*)&lds[(wave * 16 + row16) * LDSP + ks * 32 + kgrp * 8];

  f32x4 acc[8];
  #pragma unroll
  for (int ct = 0; ct < 8; ++ct) {
    acc[ct] = (f32x4){0.0f, 0.0f, 0.0f, 0.0f};
    const half8* wrow =
        (const half8*)(Wt + (size_t)(ct * 16 + row16) * NFEAT);
    #pragma unroll
    for (int ks = 0; ks < 4; ++ks) {
      acc[ct] = __builtin_amdgcn_mfma_f32_16x16x32_f16(
          wrow[ks * 4 + kgrp], afrag[ks], acc[ct], 0, 0, 0);
    }
  }

  int orow = block0 + wave * 16 + row16;
  if (orow < n) {
    unsigned short* op = out + (size_t)orow * NFEAT + kgrp * 4;
    #pragma unroll
    for (int ct = 0; ct < 8; ++ct) {
      ushort4 o;
      o.x = f2h(acc[ct][0]); o.y = f2h(acc[ct][1]);
      o.z = f2h(acc[ct][2]); o.w = f2h(acc[ct][3]);
      *(ushort4*)(op + ct * 16) = o;
    }
  }
}

// gemm0 fused with Pass A (bucket histogram) — independent work.
__global__ __launch_bounds__(256) void fused_g0_hist_kernel(
    const float* __restrict__ x, const unsigned short* __restrict__ Wt0,
    unsigned short* __restrict__ hWb, int n, int gb,
    const int4* __restrict__ dst4, int* __restrict__ bcnt, int e4, int nbuc) {
  __shared__ int lds_i[64 * LDSP / 2];
  int t = threadIdx.x;
  if ((int)blockIdx.x < gb) {
    gemm_body(blockIdx.x, x, Wt0, hWb, n, (unsigned short*)lds_i);
  } else {
    int* hist = lds_i;
    hist[t] = 0;
    __syncthreads();
    int base = ((int)blockIdx.x - gb) * 1024;
    #pragma unroll
    for (int i = 0; i < 4; ++i) {
      int idx = base + t + 256 * i;
      if (idx < e4) {
        int4 d = dst4[idx];
        atomicAdd(&hist[d.x >> BSH], 1);
        atomicAdd(&hist[d.y >> BSH], 1);
        atomicAdd(&hist[d.z >> BSH], 1);
        atomicAdd(&hist[d.w >> BSH], 1);
      }
    }
    __syncthreads();
    int h = hist[t];
    if (t < nbuc && h) atomicAdd(&bcnt[t], h);
  }
}

// Pass B: exclusive scan of bucket counts (nbuc <= 256), init gcur, rowp[n]=E
__global__ __launch_bounds__(256) void scan_buckets_kernel(
    const int* __restrict__ bcnt, int* __restrict__ boff,
    int* __restrict__ gcur, int* __restrict__ rowp, int nbuc, int n, int e) {
  __shared__ int wsum[4];
  int t = threadIdx.x, lane = t & 63, wid = t >> 6;
  int v = (t < nbuc) ? bcnt[t] : 0;
  int s = v;
  #pragma unroll
  for (int off = 1; off < 64; off <<= 1) {
    int u = __shfl_up(s, off, 64);
    if (lane >= off) s += u;
  }
  if (lane == 63) wsum[wid] = s;
  __syncthreads();
  int add = 0;
  for (int w = 0; w < wid; ++w) add += wsum[w];
  int incl = add + s;
  if (t < nbuc) { boff[t] = incl - v; gcur[t] = incl - v; }
  if (t == nbuc - 1) boff[nbuc] = incl;  // == E
  if (t == 0) rowp[n] = e;
}

// Pass C: scatter (dst,src) u64 into bucket-major ebuf, block-chunked.
__global__ __launch_bounds__(256) void bucket_scatter_kernel(
    const int4* __restrict__ src4, const int4* __restrict__ dst4,
    int* __restrict__ gcur, unsigned long long* __restrict__ ebuf, int e4) {
  __shared__ int hist[256];
  __shared__ int cbase[256];
  __shared__ int cur[256];
  int t = threadIdx.x;
  hist[t] = 0; cur[t] = 0;
  __syncthreads();
  int base = blockIdx.x * 1024;
  int4 dv[4], sv[4];
  bool val[4];
  #pragma unroll
  for (int i = 0; i < 4; ++i) {
    int idx = base + t + 256 * i;
    val[i] = idx < e4;
    if (val[i]) {
      dv[i] = dst4[idx];
      sv[i] = src4[idx];
      atomicAdd(&hist[dv[i].x >> BSH], 1);
      atomicAdd(&hist[dv[i].y >> BSH], 1);
      atomicAdd(&hist[dv[i].z >> BSH], 1);
      atomicAdd(&hist[dv[i].w >> BSH], 1);
    }
  }
  __syncthreads();
  int h = hist[t];
  if (h) cbase[t] = atomicAdd(&gcur[t], h);  // hist[t]==0 for t>=nbuc
  __syncthreads();
  #pragma unroll
  for (int i = 0; i < 4; ++i) {
    if (val[i]) {
      int d, s, b, p;
      d = dv[i].x; s = sv[i].x; b = d >> BSH;
      p = cbase[b] + atomicAdd(&cur[b], 1);
      ebuf[p] = ((unsigned long long)(unsigned)d << 32) | (unsigned)s;
      d = dv[i].y; s = sv[i].y; b = d >> BSH;
      p = cbase[b] + atomicAdd(&cur[b], 1);
      ebuf[p] = ((unsigned long long)(unsigned)d << 32) | (unsigned)s;
      d = dv[i].z; s = sv[i].z; b = d >> BSH;
      p = cbase[b] + atomicAdd(&cur[b], 1);
      ebuf[p] = ((unsigned long long)(unsigned)d << 32) | (unsigned)s;
      d = dv[i].w; s = sv[i].w; b = d >> BSH;
      p = cbase[b] + atomicAdd(&cur[b], 1);
      ebuf[p] = ((unsigned long long)(unsigned)d << 32) | (unsigned)s;
    }
  }
}

// Pass D1: per-bucket degree hist (LDS) + local scan -> rowp, dinv.
__global__ __launch_bounds__(256) void bucket_deg_kernel(
    const unsigned long long* __restrict__ ebuf, const int* __restrict__ boff,
    int* __restrict__ rowp, float* __restrict__ dinv, int n) {
  __shared__ int deg[BWID];
  __shared__ int wsum[4];
  int t = threadIdx.x;
  int b = blockIdx.x, node0 = b << BSH;
  deg[t] = 0; deg[t + 256] = 0;
  __syncthreads();
  int ebeg = boff[b], eend = boff[b + 1];
  for (int i = ebeg + t; i < eend; i += 256) {
    int d = (int)(ebuf[i] >> 32);
    atomicAdd(&deg[d - node0], 1);
  }
  __syncthreads();
  int d0 = deg[2 * t], d1 = deg[2 * t + 1];
  int s = d0 + d1;
  int lane = t & 63, wid = t >> 6;
  int sc = s;
  #pragma unroll
  for (int off = 1; off < 64; off <<= 1) {
    int u = __shfl_up(sc, off, 64);
    if (lane >= off) sc += u;
  }
  if (lane == 63) wsum[wid] = sc;
  __syncthreads();
  int add = 0;
  for (int w = 0; w < wid; ++w) add += wsum[w];
  int excl = ebeg + add + sc - s;  // rowp of node 2t in this bucket
  int node = node0 + 2 * t;
  if (node < n) {
    rowp[node] = excl;
    dinv[node] = rsqrtf(1.0f + (float)d0);
  }
  if (node + 1 < n) {
    rowp[node + 1] = excl + d0;
    dinv[node + 1] = rsqrtf(1.0f + (float)d1);
  }
}

// Pass D2: per-bucket fine scatter into colw2 (writes confined to the
// bucket's ~64KB region -> one block/XCD -> L2 lines merge).
// colw2 entry: word0 = bo = src*256 (byte offset), word1 = f16(w) packed
// into both halves -> aggregate needs ZERO per-edge VALU prep.
__global__ __launch_bounds__(256) void bucket_fill_kernel(
    const unsigned long long* __restrict__ ebuf, const int* __restrict__ boff,
    const int* __restrict__ rowp, const float* __restrict__ dinv,
    unsigned long long* __restrict__ colw2, int n) {
  __shared__ int cur[BWID];
  int t = threadIdx.x;
  int b = blockIdx.x, node0 = b << BSH;
  for (int k = t; k < BWID; k += 256) {
    int node = node0 + k;
    cur[k] = (node < n) ? rowp[node] : 0;
  }
  __syncthreads();
  int ebeg = boff[b], eend = boff[b + 1];
  for (int i = ebeg + t; i < eend; i += 256) {
    unsigned long long p = ebuf[i];
    int d = (int)(p >> 32);
    int s = (int)(unsigned int)p;
    float w = dinv[s] * dinv[d];
    unsigned int wh = f2h(w);
    unsigned int wpk = (wh << 16) | wh;
    unsigned int bo = (unsigned int)s << 8;  // s * 256
    int pos = atomicAdd(&cur[d - node0], 1);
    colw2[pos] = ((unsigned long long)wpk << 32) | bo;
  }
}

// W fp32 [k][n] -> Wt0 bf16 [n][k]; Wt1/Wt2 f16 [n][k]
__global__ __launch_bounds__(256) void wprep_kernel(
    const float* __restrict__ W0, const float* __restrict__ W1,
    const float* __restrict__ W2, unsigned short* __restrict__ Wt0,
    unsigned short* __restrict__ Wt1, unsigned short* __restrict__ Wt2) {
  int which = blockIdx.x >> 6;
  int i = (blockIdx.x & 63) * 256 + threadIdx.x;
  int nn = i >> 7, k = i & 127;
  const float* W = which == 0 ? W0 : (which == 1 ? W1 : W2);
  float v = W[k * 128 + nn];
  if (which == 0) {
    Wt0[nn * 128 + k] = f2bf(v);
  } else {
    (which == 1 ? Wt1 : Wt2)[nn * 128 + k] = f2h(v);
  }
}

// ---------------- Aggregate (quarter-per-node, shfl-free) -------------
// 16-lane quarter per node; lane l owns features 8l..8l+7 (16B of row).
// Per 4-edge step: 4 u64 colw2 loads (quarter-uniform, broadcast), tail
// clamped branch-free; 4 independent dwordx4 gathers (one instruction =
// 4 different rows across the wave's quarters); 16 v_pk_fma_f16.
// No __shfl, no reduce. mode 0: out f16. 1: +resid f16. 2: out f32.
__global__ __launch_bounds__(256) void aggregate_kernel(
    const unsigned short* __restrict__ hWb, const int* __restrict__ row_ptr,
    const unsigned long long* __restrict__ colw2, const float* __restrict__ dinv,
    const float* __restrict__ bias, const unsigned int* __restrict__ resid16,
    void* __restrict__ out, int n, int mode) {
  int t = threadIdx.x;
  int lane = t & 63;
  int q = lane >> 4;        // quarter id within wave
  int l = lane & 15;        // lane within quarter
  int node = blockIdx.x * 16 + (t >> 6) * 4 + q;
  bool active = node < n;
  int nc = active ? node : n - 1;
  int beg = row_ptr[nc];
  int end = active ? row_ptr[nc + 1] : beg;
  int lb = l * 16;          // byte offset within a 256B row
  const char* hWbc = (const char*)hWb;

  // hoisted epilogue loads (independent of the gather stream)
  i32x4 sv = *(const i32x4*)(hWbc + (size_t)nc * 256 + (unsigned)lb);
  const f32x4* b4 = (const f32x4*)bias;
  f32x4 bv0 = b4[l * 2];
  f32x4 bv1 = b4[l * 2 + 1];
  i32x4 rv = (i32x4){0, 0, 0, 0};
  if (mode >= 1) {
    rv = __builtin_nontemporal_load(
        (const i32x4*)((const char*)resid16 + (size_t)nc * 256 + (unsigned)lb));
  }
  float di = dinv[nc];

  h16x2 acch[4];
  #pragma unroll
  for (int m = 0; m < 4; ++m) acch[m] = (h16x2){(_Float16)0.0f, (_Float16)0.0f};

  for (int c = beg; c < end; c += 4) {
    int i1 = c + 1 < end ? c + 1 : end - 1;
    int i2 = c + 2 < end ? c + 2 : end - 1;
    int i3 = c + 3 < end ? c + 3 : end - 1;
    unsigned long long e0 = __builtin_nontemporal_load(&colw2[c]);
    unsigned long long e1 = __builtin_nontemporal_load(&colw2[i1]);
    unsigned long long e2 = __builtin_nontemporal_load(&colw2[i2]);
    unsigned long long e3 = __builtin_nontemporal_load(&colw2[i3]);
    unsigned int bo0 = (unsigned int)e0, w0 = (unsigned int)(e0 >> 32);
    unsigned int bo1 = (unsigned int)e1, w1 = (unsigned int)(e1 >> 32);
    unsigned int bo2 = (unsigned int)e2, w2 = (unsigned int)(e2 >> 32);
    unsigned int bo3 = (unsigned int)e3, w3 = (unsigned int)(e3 >> 32);
    if (c + 1 >= end) w1 = 0;   // clamped dup edges contribute 0
    if (c + 2 >= end) w2 = 0;
    if (c + 3 >= end) w3 = 0;
    // 4 independent gathers (each instruction: 4 rows across quarters)
    i32x4 p0 = *(const i32x4*)(hWbc + (bo0 + (unsigned int)lb));
    i32x4 p1 = *(const i32x4*)(hWbc + (bo1 + (unsigned int)lb));
    i32x4 p2 = *(const i32x4*)(hWbc + (bo2 + (unsigned int)lb));
    i32x4 p3 = *(const i32x4*)(hWbc + (bo3 + (unsigned int)lb));
    h16x2 h0 = u2h2(w0), h1 = u2h2(w1), h2 = u2h2(w2), h3 = u2h2(w3);
    #pragma unroll
    for (int m = 0; m < 4; ++m) acch[m] += h0 * u2h2((unsigned int)p0[m]);
    #pragma unroll
    for (int m = 0; m < 4; ++m) acch[m] += h1 * u2h2((unsigned int)p1[m]);
    #pragma unroll
    for (int m = 0; m < 4; ++m) acch[m] += h2 * u2h2((unsigned int)p2[m]);
    #pragma unroll
    for (int m = 0; m < 4; ++m) acch[m] += h3 * u2h2((unsigned int)p3[m]);
  }

  // epilogue: 8 features per lane, no cross-lane traffic at all
  float dii = di * di;
  float f[8];
  #pragma unroll
  for (int m = 0; m < 4; ++m) {
    h16x2 sm = u2h2((unsigned int)sv[m]);
    h16x2 rm = u2h2((unsigned int)rv[m]);
    f[2 * m]     = (float)acch[m].x + dii * (float)sm.x + (float)rm.x;
    f[2 * m + 1] = (float)acch[m].y + dii * (float)sm.y + (float)rm.y;
  }
  f[0] += bv0[0]; f[1] += bv0[1]; f[2] += bv0[2]; f[3] += bv0[3];
  f[4] += bv1[0]; f[5] += bv1[1]; f[6] += bv1[2]; f[7] += bv1[3];
  #pragma unroll
  for (int k = 0; k < 8; ++k) f[k] = elu_fast(f[k]);

  if (active) {
    if (mode == 2) {
      f32x4 oa = (f32x4){f[0], f[1], f[2], f[3]};
      f32x4 ob = (f32x4){f[4], f[5], f[6], f[7]};
      float* op = (float*)out + (size_t)node * 128 + (unsigned)(l * 8);
      __builtin_nontemporal_store(oa, (f32x4*)op);
      __builtin_nontemporal_store(ob, (f32x4*)(op + 4));
    } else {
      i32x4 ov;
      ov[0] = (int)(((unsigned)f2h(f[1]) << 16) | f2h(f[0]));
      ov[1] = (int)(((unsigned)f2h(f[3]) << 16) | f2h(f[2]));
      ov[2] = (int)(((unsigned)f2h(f[5]) << 16) | f2h(f[4]));
      ov[3] = (int)(((unsigned)f2h(f[7]) << 16) | f2h(f[6]));
      __builtin_nontemporal_store(
          ov, (i32x4*)((char*)out + (size_t)node * 256 + (unsigned)lb));
    }
  }
}

extern "C" void kernel_launch(void* const* d_in, const int* in_sizes, int n_in,
                              void* d_out, int out_size, void* d_ws, size_t ws_size,
                              hipStream_t stream) {
  const float* x  = (const float*)d_in[0];
  const int* eidx = (const int*)d_in[1];
  const float* W0 = (const float*)d_in[2];
  const float* b0 = (const float*)d_in[3];
  const float* W1 = (const float*)d_in[4];
  const float* b1 = (const float*)d_in[5];
  const float* W2 = (const float*)d_in[6];
  const float* b2 = (const float*)d_in[7];
  float* outp = (float*)d_out;

  const int N = in_sizes[0] / NFEAT;   // 100000
  const int E = in_sizes[1] / 2;       // 1600000 (divisible by 4)
  const int* src = eidx;
  const int* dst = eidx + E;
  const int NBUC = (N + BWID - 1) >> BSH;  // 196
  const int e4 = E / 4;

  // workspace layout (all chunk sizes 1KB-multiples)
  const size_t S1 = 401408;                   // > (N+1)*4
  const size_t SBK = 1024;                    // > (NBUC+1)*4
  const size_t SW = 32768;                    // 128*128*2
  const size_t SE2 = (size_t)E * 8;           // 12.8 MB colw2 u64 entries
  const size_t SEB = (size_t)E * 8;           // 12.8 MB bucketed (dst,src)
  const size_t SH = (size_t)N * NFEAT * 2;    // 25.6 MB f16 features
  char* p = (char*)d_ws;
  float* dinv   = (float*)p;            p += S1;
  int*   rowp   = (int*)p;              p += S1;
  int*   bcnt   = (int*)p;              p += SBK;
  int*   boff   = (int*)p;              p += SBK;
  int*   gcur   = (int*)p;              p += SBK;
  unsigned short* Wt0 = (unsigned short*)p;  p += SW;  // bf16
  unsigned short* Wt1 = (unsigned short*)p;  p += SW;  // f16
  unsigned short* Wt2 = (unsigned short*)p;  p += SW;  // f16
  unsigned long long* colw2 = (unsigned long long*)p; p += SE2;
  unsigned long long* ebuf = (unsigned long long*)p; p += SEB;
  unsigned short* hWb = (unsigned short*)p;  p += SH;  // f16 gather table
  unsigned short* hA  = (unsigned short*)p;  p += SH;  // f16 h
  unsigned short* hB  = (unsigned short*)p;  p += SH;  // f16 h

  int gemm_blocks = (N + 63) / 64;        // 1563
  int cbk = (e4 + 1023) / 1024;           // 391 (4096 edges/block)
  int agg_blocks = (N + 15) / 16;         // 6250 (16 nodes/block)

  // ---- prep + fused {gemm0, Pass A} ----
  wprep_kernel<<<192, 256, 0, stream>>>(W0, W1, W2, Wt0, Wt1, Wt2);
  hipMemsetAsync(bcnt, 0, (size_t)NBUC * 4, stream);
  fused_g0_hist_kernel<<<gemm_blocks + cbk, 256, 0, stream>>>(
      x, Wt0, hWb, N, gemm_blocks, (const int4*)dst, bcnt, e4, NBUC);

  // ---- bucketed CSR build ----
  scan_buckets_kernel<<<1, 256, 0, stream>>>(bcnt, boff, gcur, rowp,
                                             NBUC, N, E);
  bucket_scatter_kernel<<<cbk, 256, 0, stream>>>(
      (const int4*)src, (const int4*)dst, gcur, ebuf, e4);
  bucket_deg_kernel<<<NBUC, 256, 0, stream>>>(ebuf, boff, rowp, dinv, N);
  bucket_fill_kernel<<<NBUC, 256, 0, stream>>>(ebuf, boff, rowp, dinv,
                                               colw2, N);

  // ---- layer 0 aggregate (gemm0 already done): out hA f16 ----
  aggregate_kernel<<<agg_blocks, 256, 0, stream>>>(
      hWb, rowp, colw2, dinv, b0, nullptr, hA, N, 0);
  // ---- layer 1 ----
  gemm_f16_kernel<<<gemm_blocks, 256, 0, stream>>>(hA, Wt1, hWb, N);
  aggregate_kernel<<<agg_blocks, 256, 0, stream>>>(
      hWb, rowp, colw2, dinv, b1, (const unsigned int*)hA, hB, N, 1);
  // ---- layer 2, write d_out f32 ----
  gemm_f16_kernel<<<gemm_blocks, 256, 0, stream>>>(hB, Wt2, hWb, N);
  aggregate_kernel<<<agg_blocks, 256, 0, stream>>>(
      hWb, rowp, colw2, dinv, b2, (const unsigned int*)hB, outp, N, 2);
}

// Round 10
// 459.922 us; speedup vs baseline: 1.0530x; 1.0530x over previous
//
#include <hip/hip_runtime.h>
#include <math.h>

// GCN: h = elu(D^-1/2 (A+I) D^-1/2 (h W) + b [+ resid])
// N=100000 nodes, E=1600000 edges, 128 features per layer.
//
// R17 changes vs R16 (484us, agg 76us @ VALU 17.6% -- REGRESSION) and
// R15 (450us, agg 64.4us):
//  R16 post-mortem: quarter-per-node numerics fine, VALU fine, but the
//  per-iteration colw2->gather DEPENDENT chain killed MLP (R14 decoupled
//  metadata via one coalesced load per 64 edges + register shfl).
//  - R17 keeps quarter-per-node (no shfl-reduce, lane owns 8 features)
//    but decouples metadata: each lane loads ITS OWN colw2 entry (16
//    entries/quarter, coalesced 8B/lane), distributes via in-quarter
//    __shfl (1 shfl instr serves all 4 quarters = 0.5 shfl/edge).
//  - 8 gathers issued back-to-back (depth/quarter now scales with deg
//    ~17, not deg/4): ~160 outstanding reqs/CU vs R14's ~96.
//  - Dead-quarter chunks skipped by quarter-uniform branch (exec mask
//    suppresses their requests); partial tails gather row 0 with w=0.

#define NFEAT 128
#define LDSP 136   // LDS row pitch in shorts (128 + 8 pad)
#define BSH 9      // bucket shift: 512 nodes/bucket
#define BWID 512

typedef short short8 __attribute__((ext_vector_type(8)));
typedef unsigned short ushort8 __attribute__((ext_vector_type(8)));
typedef _Float16 half8 __attribute__((ext_vector_type(8)));
typedef _Float16 h16x2 __attribute__((ext_vector_type(2)));
typedef float f32x4 __attribute__((ext_vector_type(4)));
typedef float f32x2 __attribute__((ext_vector_type(2)));
typedef int i32x4 __attribute__((ext_vector_type(4)));

static __device__ __forceinline__ unsigned short f2bf(float f) {
  union { float f; unsigned int u; } v; v.f = f;
  unsigned int r = v.u + 0x7fffu + ((v.u >> 16) & 1u);  // RNE (finite values)
  return (unsigned short)(r >> 16);
}
static __device__ __forceinline__ unsigned short f2h(float f) {
  union { _Float16 h; unsigned short u; } c; c.h = (_Float16)f; return c.u;
}
static __device__ __forceinline__ h16x2 u2h2(unsigned int u) {
  union { unsigned int i; h16x2 h; } c; c.i = u; return c.h;
}
static __device__ __forceinline__ float elu_fast(float a) {
  return a > 0.0f ? a : (__expf(a) - 1.0f);
}

// ---------------- GEMM body, fp32 input -> bf16 MFMA, f16 out (L0) ----
static __device__ __forceinline__ void gemm_body(
    int gblk, const float* __restrict__ h, const unsigned short* __restrict__ Wt,
    unsigned short* __restrict__ out, int n, unsigned short* lds) {
  int t = threadIdx.x;
  int block0 = gblk * 64;

  const f32x4* h4 = (const f32x4*)h;
  #pragma unroll
  for (int i = 0; i < 8; ++i) {
    int idx = t + 256 * i;          // 0..2047
    int r = idx >> 5, c = idx & 31; // row, float4-col
    int grow = block0 + r; if (grow >= n) grow = n - 1;
    f32x4 v = __builtin_nontemporal_load(&h4[(size_t)grow * 32 + c]);
    ushort4 b;
    b.x = f2bf(v.x); b.y = f2bf(v.y); b.z = f2bf(v.z); b.w = f2bf(v.w);
    *(ushort4*)&lds[r * LDSP + c * 4] = b;
  }
  __syncthreads();

  int lane = t & 63, wave = t >> 6;
  int row16 = lane & 15;
  int kgrp = lane >> 4;

  short8 afrag[4];
  #pragma unroll
  for (int ks = 0; ks < 4; ++ks)
    afrag[ks] =
        *(const short8*)&lds[(wave * 16 + row16) * LDSP + ks * 32 + kgrp * 8];

  f32x4 acc[8];
  #pragma unroll
  for (int ct = 0; ct < 8; ++ct) {
    acc[ct] = (f32x4){0.0f, 0.0f, 0.0f, 0.0f};
    const short8* wrow =
        (const short8*)(Wt + (size_t)(ct * 16 + row16) * NFEAT);
    #pragma unroll
    for (int ks = 0; ks < 4; ++ks) {
      acc[ct] = __builtin_amdgcn_mfma_f32_16x16x32_bf16(
          wrow[ks * 4 + kgrp], afrag[ks], acc[ct], 0, 0, 0);
    }
  }

  int orow = block0 + wave * 16 + row16;
  if (orow < n) {
    unsigned short* op = out + (size_t)orow * NFEAT + kgrp * 4;
    #pragma unroll
    for (int ct = 0; ct < 8; ++ct) {
      ushort4 o;
      o.x = f2h(acc[ct][0]); o.y = f2h(acc[ct][1]);
      o.z = f2h(acc[ct][2]); o.w = f2h(acc[ct][3]);
      *(ushort4*)(op + ct * 16) = o;
    }
  }
}

// ---------------- GEMM, f16 input -> f16 MFMA, f16 out (L1, L2) -------
__global__ __launch_bounds__(256) void gemm_f16_kernel(
    const unsigned short* __restrict__ h16,  // f16 bits [n][128]
    const unsigned short* __restrict__ Wt,   // f16 bits [128][128] (n-major)
    unsigned short* __restrict__ out, int n) {
  __shared__ int lds_i[64 * LDSP / 2];
  unsigned short* lds = (unsigned short*)lds_i;
  int t = threadIdx.x;
  int block0 = blockIdx.x * 64;

  const ushort8* h8 = (const ushort8*)h16;
  #pragma unroll
  for (int i = 0; i < 4; ++i) {
    int idx = t + 256 * i;          // 0..1023
    int r = idx >> 4, c = idx & 15; // row, 8-elem col
    int grow = block0 + r; if (grow >= n) grow = n - 1;
    ushort8 v = __builtin_nontemporal_load(&h8[(size_t)grow * 16 + c]);
    *(ushort8*)&lds[r * LDSP + c * 8] = v;
  }
  __syncthreads();

  int lane = t & 63, wave = t >> 6;
  int row16 = lane & 15;
  int kgrp = lane >> 4;

  half8 afrag[4];
  #pragma unroll
  for (int ks = 0; ks < 4; ++ks)
    afrag[ks] =
        *(const half8*)&lds[(wave * 16 + row16) * LDSP + ks * 32 + kgrp * 8];

  f32x4 acc[8];
  #pragma unroll
  for (int ct = 0; ct < 8; ++ct) {
    acc[ct] = (f32x4){0.0f, 0.0f, 0.0f, 0.0f};
    const half8* wrow =
        (const half8*)(Wt + (size_t)(ct * 16 + row16) * NFEAT);
    #pragma unroll
    for (int ks = 0; ks < 4; ++ks) {
      acc[ct] = __builtin_amdgcn_mfma_f32_16x16x32_f16(
          wrow[ks * 4 + kgrp], afrag[ks], acc[ct], 0, 0, 0);
    }
  }

  int orow = block0 + wave * 16 + row16;
  if (orow < n) {
    unsigned short* op = out + (size_t)orow * NFEAT + kgrp * 4;
    #pragma unroll
    for (int ct = 0; ct < 8; ++ct) {
      ushort4 o;
      o.x = f2h(acc[ct][0]); o.y = f2h(acc[ct][1]);
      o.z = f2h(acc[ct][2]); o.w = f2h(acc[ct][3]);
      *(ushort4*)(op + ct * 16) = o;
    }
  }
}

// gemm0 fused with Pass A (bucket histogram) — independent work.
__global__ __launch_bounds__(256) void fused_g0_hist_kernel(
    const float* __restrict__ x, const unsigned short* __restrict__ Wt0,
    unsigned short* __restrict__ hWb, int n, int gb,
    const int4* __restrict__ dst4, int* __restrict__ bcnt, int e4, int nbuc) {
  __shared__ int lds_i[64 * LDSP / 2];
  int t = threadIdx.x;
  if ((int)blockIdx.x < gb) {
    gemm_body(blockIdx.x, x, Wt0, hWb, n, (unsigned short*)lds_i);
  } else {
    int* hist = lds_i;
    hist[t] = 0;
    __syncthreads();
    int base = ((int)blockIdx.x - gb) * 1024;
    #pragma unroll
    for (int i = 0; i < 4; ++i) {
      int idx = base + t + 256 * i;
      if (idx < e4) {
        int4 d = dst4[idx];
        atomicAdd(&hist[d.x >> BSH], 1);
        atomicAdd(&hist[d.y >> BSH], 1);
        atomicAdd(&hist[d.z >> BSH], 1);
        atomicAdd(&hist[d.w >> BSH], 1);
      }
    }
    __syncthreads();
    int h = hist[t];
    if (t < nbuc && h) atomicAdd(&bcnt[t], h);
  }
}

// Pass B: exclusive scan of bucket counts (nbuc <= 256), init gcur, rowp[n]=E
__global__ __launch_bounds__(256) void scan_buckets_kernel(
    const int* __restrict__ bcnt, int* __restrict__ boff,
    int* __restrict__ gcur, int* __restrict__ rowp, int nbuc, int n, int e) {
  __shared__ int wsum[4];
  int t = threadIdx.x, lane = t & 63, wid = t >> 6;
  int v = (t < nbuc) ? bcnt[t] : 0;
  int s = v;
  #pragma unroll
  for (int off = 1; off < 64; off <<= 1) {
    int u = __shfl_up(s, off, 64);
    if (lane >= off) s += u;
  }
  if (lane == 63) wsum[wid] = s;
  __syncthreads();
  int add = 0;
  for (int w = 0; w < wid; ++w) add += wsum[w];
  int incl = add + s;
  if (t < nbuc) { boff[t] = incl - v; gcur[t] = incl - v; }
  if (t == nbuc - 1) boff[nbuc] = incl;  // == E
  if (t == 0) rowp[n] = e;
}

// Pass C: scatter (dst,src) u64 into bucket-major ebuf, block-chunked.
__global__ __launch_bounds__(256) void bucket_scatter_kernel(
    const int4* __restrict__ src4, const int4* __restrict__ dst4,
    int* __restrict__ gcur, unsigned long long* __restrict__ ebuf, int e4) {
  __shared__ int hist[256];
  __shared__ int cbase[256];
  __shared__ int cur[256];
  int t = threadIdx.x;
  hist[t] = 0; cur[t] = 0;
  __syncthreads();
  int base = blockIdx.x * 1024;
  int4 dv[4], sv[4];
  bool val[4];
  #pragma unroll
  for (int i = 0; i < 4; ++i) {
    int idx = base + t + 256 * i;
    val[i] = idx < e4;
    if (val[i]) {
      dv[i] = dst4[idx];
      sv[i] = src4[idx];
      atomicAdd(&hist[dv[i].x >> BSH], 1);
      atomicAdd(&hist[dv[i].y >> BSH], 1);
      atomicAdd(&hist[dv[i].z >> BSH], 1);
      atomicAdd(&hist[dv[i].w >> BSH], 1);
    }
  }
  __syncthreads();
  int h = hist[t];
  if (h) cbase[t] = atomicAdd(&gcur[t], h);  // hist[t]==0 for t>=nbuc
  __syncthreads();
  #pragma unroll
  for (int i = 0; i < 4; ++i) {
    if (val[i]) {
      int d, s, b, p;
      d = dv[i].x; s = sv[i].x; b = d >> BSH;
      p = cbase[b] + atomicAdd(&cur[b], 1);
      ebuf[p] = ((unsigned long long)(unsigned)d << 32) | (unsigned)s;
      d = dv[i].y; s = sv[i].y; b = d >> BSH;
      p = cbase[b] + atomicAdd(&cur[b], 1);
      ebuf[p] = ((unsigned long long)(unsigned)d << 32) | (unsigned)s;
      d = dv[i].z; s = sv[i].z; b = d >> BSH;
      p = cbase[b] + atomicAdd(&cur[b], 1);
      ebuf[p] = ((unsigned long long)(unsigned)d << 32) | (unsigned)s;
      d = dv[i].w; s = sv[i].w; b = d >> BSH;
      p = cbase[b] + atomicAdd(&cur[b], 1);
      ebuf[p] = ((unsigned long long)(unsigned)d << 32) | (unsigned)s;
    }
  }
}

// Pass D1: per-bucket degree hist (LDS) + local scan -> rowp, dinv.
__global__ __launch_bounds__(256) void bucket_deg_kernel(
    const unsigned long long* __restrict__ ebuf, const int* __restrict__ boff,
    int* __restrict__ rowp, float* __restrict__ dinv, int n) {
  __shared__ int deg[BWID];
  __shared__ int wsum[4];
  int t = threadIdx.x;
  int b = blockIdx.x, node0 = b << BSH;
  deg[t] = 0; deg[t + 256] = 0;
  __syncthreads();
  int ebeg = boff[b], eend = boff[b + 1];
  for (int i = ebeg + t; i < eend; i += 256) {
    int d = (int)(ebuf[i] >> 32);
    atomicAdd(&deg[d - node0], 1);
  }
  __syncthreads();
  int d0 = deg[2 * t], d1 = deg[2 * t + 1];
  int s = d0 + d1;
  int lane = t & 63, wid = t >> 6;
  int sc = s;
  #pragma unroll
  for (int off = 1; off < 64; off <<= 1) {
    int u = __shfl_up(sc, off, 64);
    if (lane >= off) sc += u;
  }
  if (lane == 63) wsum[wid] = sc;
  __syncthreads();
  int add = 0;
  for (int w = 0; w < wid; ++w) add += wsum[w];
  int excl = ebeg + add + sc - s;  // rowp of node 2t in this bucket
  int node = node0 + 2 * t;
  if (node < n) {
    rowp[node] = excl;
    dinv[node] = rsqrtf(1.0f + (float)d0);
  }
  if (node + 1 < n) {
    rowp[node + 1] = excl + d0;
    dinv[node + 1] = rsqrtf(1.0f + (float)d1);
  }
}

// Pass D2: per-bucket fine scatter into colw2 (writes confined to the
// bucket's ~64KB region -> one block/XCD -> L2 lines merge).
// colw2 entry: word0 = bo = src*256 (byte offset), word1 = f16(w) packed
// into both halves -> aggregate needs ZERO per-edge VALU prep.
__global__ __launch_bounds__(256) void bucket_fill_kernel(
    const unsigned long long* __restrict__ ebuf, const int* __restrict__ boff,
    const int* __restrict__ rowp, const float* __restrict__ dinv,
    unsigned long long* __restrict__ colw2, int n) {
  __shared__ int cur[BWID];
  int t = threadIdx.x;
  int b = blockIdx.x, node0 = b << BSH;
  for (int k = t; k < BWID; k += 256) {
    int node = node0 + k;
    cur[k] = (node < n) ? rowp[node] : 0;
  }
  __syncthreads();
  int ebeg = boff[b], eend = boff[b + 1];
  for (int i = ebeg + t; i < eend; i += 256) {
    unsigned long long p = ebuf[i];
    int d = (int)(p >> 32);
    int s = (int)(unsigned int)p;
    float w = dinv[s] * dinv[d];
    unsigned int wh = f2h(w);
    unsigned int wpk = (wh << 16) | wh;
    unsigned int bo = (unsigned int)s << 8;  // s * 256
    int pos = atomicAdd(&cur[d - node0], 1);
    colw2[pos] = ((unsigned long long)wpk << 32) | bo;
  }
}

// W fp32 [k][n] -> Wt0 bf16 [n][k]; Wt1/Wt2 f16 [n][k]
__global__ __launch_bounds__(256) void wprep_kernel(
    const float* __restrict__ W0, const float* __restrict__ W1,
    const float* __restrict__ W2, unsigned short* __restrict__ Wt0,
    unsigned short* __restrict__ Wt1, unsigned short* __restrict__ Wt2) {
  int which = blockIdx.x >> 6;
  int i = (blockIdx.x & 63) * 256 + threadIdx.x;
  int nn = i >> 7, k = i & 127;
  const float* W = which == 0 ? W0 : (which == 1 ? W1 : W2);
  float v = W[k * 128 + nn];
  if (which == 0) {
    Wt0[nn * 128 + k] = f2bf(v);
  } else {
    (which == 1 ? Wt1 : Wt2)[nn * 128 + k] = f2h(v);
  }
}

// ---------------- Aggregate (quarter-per-node, decoupled metadata) ----
// 16-lane quarter per node; lane l owns features 8l..8l+7 (16B of row).
// Per 16-edge chunk: each lane loads ITS colw2 entry (coalesced 8B);
// in-quarter __shfl distributes entry j to all 16 lanes (one shfl
// instruction serves all 4 quarters). Two groups of 8 back-to-back
// dwordx4 gathers (each instruction = 4 rows across quarters).
// Dead-quarter chunks skipped by quarter-uniform branch; partial tails
// carry w=0 (gather row 0, L2-hot). No cross-lane reduce.
// mode 0: out f16. 1: +resid f16. 2: out f32 (final).
__global__ __launch_bounds__(256) void aggregate_kernel(
    const unsigned short* __restrict__ hWb, const int* __restrict__ row_ptr,
    const unsigned long long* __restrict__ colw2, const float* __restrict__ dinv,
    const float* __restrict__ bias, const unsigned int* __restrict__ resid16,
    void* __restrict__ out, int n, int mode) {
  int t = threadIdx.x;
  int lane = t & 63;
  int qb = lane & 48;       // quarter base lane (q*16)
  int l = lane & 15;        // lane within quarter
  int node = blockIdx.x * 16 + (t >> 6) * 4 + (qb >> 4);
  bool active = node < n;
  int nc = active ? node : n - 1;
  int beg = row_ptr[nc];
  int end = active ? row_ptr[nc + 1] : beg;
  int cnt = end - beg;
  int lb = l * 16;          // byte offset within a 256B row
  const char* hWbc = (const char*)hWb;

  // hoisted epilogue loads (independent of the gather stream)
  i32x4 sv = *(const i32x4*)(hWbc + (size_t)nc * 256 + (unsigned)lb);
  const f32x4* b4 = (const f32x4*)bias;
  f32x4 bv0 = b4[l * 2];
  f32x4 bv1 = b4[l * 2 + 1];
  i32x4 rv = (i32x4){0, 0, 0, 0};
  if (mode >= 1) {
    rv = __builtin_nontemporal_load(
        (const i32x4*)((const char*)resid16 + (size_t)nc * 256 + (unsigned)lb));
  }
  float di = dinv[nc];

  h16x2 acch[4];
  #pragma unroll
  for (int m = 0; m < 4; ++m) acch[m] = (h16x2){(_Float16)0.0f, (_Float16)0.0f};

  for (int cb = 0; __any(cb < cnt); cb += 16) {
    // coalesced metadata: lane l loads entry cb+l of its quarter's list
    int myidx = beg + cb + l;
    unsigned long long e = 0;            // invalid lanes: bo=0, w=0
    if (myidx < end) e = __builtin_nontemporal_load(&colw2[myidx]);
    unsigned int bo = (unsigned int)e;
    unsigned int wpk = (unsigned int)(e >> 32);

    if (cb < cnt) {   // quarter-uniform: whole quarters take this branch
      #pragma unroll
      for (int g = 0; g < 2; ++g) {
        unsigned int bj[8], wj[8];
        #pragma unroll
        for (int j = 0; j < 8; ++j) {
          bj[j] = (unsigned int)__shfl((int)bo, qb + g * 8 + j, 64);
          wj[j] = (unsigned int)__shfl((int)wpk, qb + g * 8 + j, 64);
        }
        // 8 independent gathers, issued back-to-back
        i32x4 pv[8];
        #pragma unroll
        for (int j = 0; j < 8; ++j)
          pv[j] = *(const i32x4*)(hWbc + (bj[j] + (unsigned int)lb));
        #pragma unroll
        for (int j = 0; j < 8; ++j) {
          h16x2 hw = u2h2(wj[j]);
          #pragma unroll
          for (int m = 0; m < 4; ++m)
            acch[m] += hw * u2h2((unsigned int)pv[j][m]);
        }
      }
    }
  }

  // epilogue: 8 features per lane, no cross-lane traffic at all
  float dii = di * di;
  float f[8];
  #pragma unroll
  for (int m = 0; m < 4; ++m) {
    h16x2 sm = u2h2((unsigned int)sv[m]);
    h16x2 rm = u2h2((unsigned int)rv[m]);
    f[2 * m]     = (float)acch[m].x + dii * (float)sm.x + (float)rm.x;
    f[2 * m + 1] = (float)acch[m].y + dii * (float)sm.y + (float)rm.y;
  }
  f[0] += bv0[0]; f[1] += bv0[1]; f[2] += bv0[2]; f[3] += bv0[3];
  f[4] += bv1[0]; f[5] += bv1[1]; f[6] += bv1[2]; f[7] += bv1[3];
  #pragma unroll
  for (int k = 0; k < 8; ++k) f[k] = elu_fast(f[k]);

  if (active) {
    if (mode == 2) {
      f32x4 oa = (f32x4){f[0], f[1], f[2], f[3]};
      f32x4 ob = (f32x4){f[4], f[5], f[6], f[7]};
      float* op = (float*)out + (size_t)node * 128 + (unsigned)(l * 8);
      __builtin_nontemporal_store(oa, (f32x4*)op);
      __builtin_nontemporal_store(ob, (f32x4*)(op + 4));
    } else {
      i32x4 ov;
      ov[0] = (int)(((unsigned)f2h(f[1]) << 16) | f2h(f[0]));
      ov[1] = (int)(((unsigned)f2h(f[3]) << 16) | f2h(f[2]));
      ov[2] = (int)(((unsigned)f2h(f[5]) << 16) | f2h(f[4]));
      ov[3] = (int)(((unsigned)f2h(f[7]) << 16) | f2h(f[6]));
      __builtin_nontemporal_store(
          ov, (i32x4*)((char*)out + (size_t)node * 256 + (unsigned)lb));
    }
  }
}

extern "C" void kernel_launch(void* const* d_in, const int* in_sizes, int n_in,
                              void* d_out, int out_size, void* d_ws, size_t ws_size,
                              hipStream_t stream) {
  const float* x  = (const float*)d_in[0];
  const int* eidx = (const int*)d_in[1];
  const float* W0 = (const float*)d_in[2];
  const float* b0 = (const float*)d_in[3];
  const float* W1 = (const float*)d_in[4];
  const float* b1 = (const float*)d_in[5];
  const float* W2 = (const float*)d_in[6];
  const float* b2 = (const float*)d_in[7];
  float* outp = (float*)d_out;

  const int N = in_sizes[0] / NFEAT;   // 100000
  const int E = in_sizes[1] / 2;       // 1600000 (divisible by 4)
  const int* src = eidx;
  const int* dst = eidx + E;
  const int NBUC = (N + BWID - 1) >> BSH;  // 196
  const int e4 = E / 4;

  // workspace layout (all chunk sizes 1KB-multiples)
  const size_t S1 = 401408;                   // > (N+1)*4
  const size_t SBK = 1024;                    // > (NBUC+1)*4
  const size_t SW = 32768;                    // 128*128*2
  const size_t SE2 = (size_t)E * 8;           // 12.8 MB colw2 u64 entries
  const size_t SEB = (size_t)E * 8;           // 12.8 MB bucketed (dst,src)
  const size_t SH = (size_t)N * NFEAT * 2;    // 25.6 MB f16 features
  char* p = (char*)d_ws;
  float* dinv   = (float*)p;            p += S1;
  int*   rowp   = (int*)p;              p += S1;
  int*   bcnt   = (int*)p;              p += SBK;
  int*   boff   = (int*)p;              p += SBK;
  int*   gcur   = (int*)p;              p += SBK;
  unsigned short* Wt0 = (unsigned short*)p;  p += SW;  // bf16
  unsigned short* Wt1 = (unsigned short*)p;  p += SW;  // f16
  unsigned short* Wt2 = (unsigned short*)p;  p += SW;  // f16
  unsigned long long* colw2 = (unsigned long long*)p; p += SE2;
  unsigned long long* ebuf = (unsigned long long*)p; p += SEB;
  unsigned short* hWb = (unsigned short*)p;  p += SH;  // f16 gather table
  unsigned short* hA  = (unsigned short*)p;  p += SH;  // f16 h
  unsigned short* hB  = (unsigned short*)p;  p += SH;  // f16 h

  int gemm_blocks = (N + 63) / 64;        // 1563
  int cbk = (e4 + 1023) / 1024;           // 391 (4096 edges/block)
  int agg_blocks = (N + 15) / 16;         // 6250 (16 nodes/block)

  // ---- prep + fused {gemm0, Pass A} ----
  wprep_kernel<<<192, 256, 0, stream>>>(W0, W1, W2, Wt0, Wt1, Wt2);
  hipMemsetAsync(bcnt, 0, (size_t)NBUC * 4, stream);
  fused_g0_hist_kernel<<<gemm_blocks + cbk, 256, 0, stream>>>(
      x, Wt0, hWb, N, gemm_blocks, (const int4*)dst, bcnt, e4, NBUC);

  // ---- bucketed CSR build ----
  scan_buckets_kernel<<<1, 256, 0, stream>>>(bcnt, boff, gcur, rowp,
                                             NBUC, N, E);
  bucket_scatter_kernel<<<cbk, 256, 0, stream>>>(
      (const int4*)src, (const int4*)dst, gcur, ebuf, e4);
  bucket_deg_kernel<<<NBUC, 256, 0, stream>>>(ebuf, boff, rowp, dinv, N);
  bucket_fill_kernel<<<NBUC, 256, 0, stream>>>(ebuf, boff, rowp, dinv,
                                               colw2, N);

  // ---- layer 0 aggregate (gemm0 already done): out hA f16 ----
  aggregate_kernel<<<agg_blocks, 256, 0, stream>>>(
      hWb, rowp, colw2, dinv, b0, nullptr, hA, N, 0);
  // ---- layer 1 ----
  gemm_f16_kernel<<<gemm_blocks, 256, 0, stream>>>(hA, Wt1, hWb, N);
  aggregate_kernel<<<agg_blocks, 256, 0, stream>>>(
      hWb, rowp, colw2, dinv, b1, (const unsigned int*)hA, hB, N, 1);
  // ---- layer 2, write d_out f32 ----
  gemm_f16_kernel<<<gemm_blocks, 256, 0, stream>>>(hB, Wt2, hWb, N);
  aggregate_kernel<<<agg_blocks, 256, 0, stream>>>(
      hWb, rowp, colw2, dinv, b2, (const unsigned int*)hB, outp, N, 2);
}